// Round 2
// baseline (80052.161 us; speedup 1.0000x reference)
//
#include <hip/hip_runtime.h>
#include <math.h>

// Problem constants
#define BB     32      // batch
#define KBM    5       // beam width
#define NR     160     // BB*KBM rows (beam-major)
#define HD     512     // hidden
#define TT     256     // encoder time steps
#define VV     5000    // vocab
#define MAXLEN 64
#define EOSID  2
#define NEGV   (-1e9f)
#define SCALEF 0.04419417382415922f  // 1/sqrt(512)
#define NBLK   256

// comparator matching jax.lax.top_k stability: value desc, index asc on ties
__device__ __forceinline__ bool viBetter(float av, int ai, float bv, int bi) {
  return (av > bv) || (av == bv && ai < bi);
}

__device__ __forceinline__ void top5_insert(float tv[5], int ti[5], float x, int v) {
  if (!viBetter(x, v, tv[4], ti[4])) return;
  tv[4] = x; ti[4] = v;
#pragma unroll
  for (int q = 4; q > 0; q--) {
    if (viBetter(tv[q], ti[q], tv[q - 1], ti[q - 1])) {
      float tf = tv[q - 1]; int tx2 = ti[q - 1];
      tv[q - 1] = tv[q]; ti[q - 1] = ti[q];
      tv[q] = tf; ti[q] = tx2;
    } else break;
  }
}

__launch_bounds__(256, 1)
__global__ void k_persist(const int* __restrict__ input_var, const float* __restrict__ enc,
                          const float* __restrict__ emb, const float* __restrict__ w_ih,
                          const float* __restrict__ w_hh, const float* __restrict__ w_out,
                          float* __restrict__ out,
                          float* h, float* A_cat, float* logits, int* tokens,
                          float* cum, int* finished, int* lengths, int* last_tok,
                          float* candV, int* candI, int* bar) {
  const int bid = blockIdx.x;
  const int tid = threadIdx.x;
  int bphase = 0;

  // ---- shared memory (sum ~86KB -> 1 block/CU; 256 blocks co-resident) ----
  __shared__ float sh_xs[32][33];         // gru
  __shared__ float sh_hs[32][33];
  __shared__ float sh_ws[6][32][32];
  __shared__ int   sh_toks[32];
  __shared__ float sh_hh[HD];             // attn
  __shared__ float sh_sc[TT];
  __shared__ float sh_red[256];           // attn + topk reductions + final
  __shared__ float sh_as[32][33];         // gemm
  __shared__ float sh_bs[32][132];
  __shared__ float sh_sv0[256 * 5]; __shared__ int sh_si0[256 * 5];
  __shared__ float sh_sv1[256 * 5]; __shared__ int sh_si1[256 * 5];
  __shared__ float sh_oc[KBM]; __shared__ int sh_ofin[KBM]; __shared__ int sh_olen[KBM];
  __shared__ int   sh_ttmp[KBM * MAXLEN];
  __shared__ int   sh_selI[KBM]; __shared__ float sh_selV[KBM];

  // ---- grid barrier: monotonic counter, device(agent)-scope acq_rel ----
  auto gbar = [&]() {
    __syncthreads();
    if (tid == 0) {
      bphase += 1;
      __hip_atomic_fetch_add(bar, 1, __ATOMIC_ACQ_REL, __HIP_MEMORY_SCOPE_AGENT);
      const int target = bphase * NBLK;
      while (__hip_atomic_load(bar, __ATOMIC_ACQUIRE, __HIP_MEMORY_SCOPE_AGENT) < target) {
        __builtin_amdgcn_s_sleep(1);
      }
    }
    __syncthreads();
  };

  // ---- init: h=0, tokens=0, last_tok=SOS ----
  {
    int gidx = bid * 256 + tid;
    const int gstride = NBLK * 256;
    for (int t = gidx; t < NR * HD; t += gstride) h[t] = 0.f;
    for (int t = gidx; t < BB * KBM * MAXLEN; t += gstride) tokens[t] = 0;
    for (int t = gidx; t < NR; t += gstride) last_tok[t] = input_var[t / KBM];
  }
  gbar();

  for (int di = 0; di < MAXLEN; di++) {
    // ================= GRU (80 blocks: 16 col-tiles x 5 row-tiles) =========
    if (bid < 80) {
      const int bx = bid & 15, by = bid >> 4;
      const int tx = tid & 31, ty = tid >> 5;
      const int i0 = bx * 32;
      const int n0 = by * 32;
      if (tid < 32) sh_toks[tid] = last_tok[n0 + tid];
      float acc[6][4];
#pragma unroll
      for (int g = 0; g < 6; g++)
#pragma unroll
        for (int rr = 0; rr < 4; rr++) acc[g][rr] = 0.f;

      for (int k0 = 0; k0 < HD; k0 += 32) {
        __syncthreads();
#pragma unroll
        for (int p = 0; p < 4; p++) {
          int idx = tid + p * 256;
          int r = idx >> 5, kk = idx & 31;
          sh_xs[r][kk] = emb[(size_t)sh_toks[r] * HD + k0 + kk];
          sh_hs[r][kk] = h[(size_t)(n0 + r) * HD + k0 + kk];
        }
#pragma unroll
        for (int p = 0; p < 24; p++) {
          int idx = tid + p * 256;
          int g = idx >> 10;
          int rem = idx & 1023;
          int kk = rem >> 5, ii = rem & 31;
          const float* W = (g < 3) ? w_ih : w_hh;
          int gc = (g < 3) ? g : (g - 3);
          sh_ws[g][kk][ii] = W[(size_t)(k0 + kk) * 1536 + gc * HD + i0 + ii];
        }
        __syncthreads();
#pragma unroll
        for (int kk = 0; kk < 32; kk++) {
          float w0 = sh_ws[0][kk][tx], w1 = sh_ws[1][kk][tx], w2 = sh_ws[2][kk][tx];
          float w3 = sh_ws[3][kk][tx], w4 = sh_ws[4][kk][tx], w5 = sh_ws[5][kk][tx];
#pragma unroll
          for (int rr = 0; rr < 4; rr++) {
            float xv = sh_xs[ty * 4 + rr][kk];
            float hv = sh_hs[ty * 4 + rr][kk];
            acc[0][rr] += xv * w0;
            acc[1][rr] += xv * w1;
            acc[2][rr] += xv * w2;
            acc[3][rr] += hv * w3;
            acc[4][rr] += hv * w4;
            acc[5][rr] += hv * w5;
          }
        }
      }
#pragma unroll
      for (int rr = 0; rr < 4; rr++) {
        int n = n0 + ty * 4 + rr;
        int i = i0 + tx;
        float hv = h[(size_t)n * HD + i];
        float z = 1.f / (1.f + expf(-(acc[0][rr] + acc[3][rr])));
        float r = 1.f / (1.f + expf(-(acc[1][rr] + acc[4][rr])));
        float nn = tanhf(acc[2][rr] + r * acc[5][rr]);
        A_cat[(size_t)n * 1024 + i] = (1.f - z) * nn + z * hv;
      }
    }
    gbar();

    // ================= attention (160 blocks: one per row) =================
    if (bid < NR) {
      const int n = bid;
      const int b = n / KBM;
      sh_hh[tid] = A_cat[(size_t)n * 1024 + tid];
      sh_hh[tid + 256] = A_cat[(size_t)n * 1024 + tid + 256];
      __syncthreads();
      const float* ep = enc + ((size_t)b * TT + tid) * HD;
      float acc = 0.f;
      for (int k = 0; k < HD; k += 4) {
        float4 e = *reinterpret_cast<const float4*>(ep + k);
        acc += sh_hh[k] * e.x + sh_hh[k + 1] * e.y + sh_hh[k + 2] * e.z + sh_hh[k + 3] * e.w;
      }
      float s = acc * SCALEF;
      sh_red[tid] = s;
      __syncthreads();
      for (int off = 128; off > 0; off >>= 1) {
        if (tid < off) sh_red[tid] = fmaxf(sh_red[tid], sh_red[tid + off]);
        __syncthreads();
      }
      float m = sh_red[0];
      __syncthreads();
      float e = expf(s - m);
      sh_red[tid] = e;
      __syncthreads();
      for (int off = 128; off > 0; off >>= 1) {
        if (tid < off) sh_red[tid] += sh_red[tid + off];
        __syncthreads();
      }
      float S = sh_red[0];
      __syncthreads();
      sh_sc[tid] = e / S;
      __syncthreads();
#pragma unroll
      for (int half = 0; half < 2; half++) {
        int i = tid + half * 256;
        float c = 0.f;
        for (int t = 0; t < TT; t++) {
          c += sh_sc[t] * enc[((size_t)b * TT + t) * HD + i];
        }
        A_cat[(size_t)n * 1024 + HD + i] = c;
      }
    }
    gbar();

    // ================= output GEMM (200 blocks: 40 col x 5 row tiles) ======
    if (bid < 200) {
      const int tx = tid & 31, ty = tid >> 5;
      const int c0 = (bid % 40) * 128;
      const int n0 = (bid / 40) * 32;
      float acc[4][4];
#pragma unroll
      for (int rr = 0; rr < 4; rr++)
#pragma unroll
        for (int cc = 0; cc < 4; cc++) acc[rr][cc] = 0.f;

      for (int k0 = 0; k0 < 1024; k0 += 32) {
        __syncthreads();
#pragma unroll
        for (int p = 0; p < 4; p++) {
          int idx = tid + p * 256;
          int r = idx >> 5, kk = idx & 31;
          sh_as[r][kk] = A_cat[(size_t)(n0 + r) * 1024 + k0 + kk];
        }
#pragma unroll
        for (int p = 0; p < 16; p++) {
          int idx = tid + p * 256;
          int kk = idx >> 7, c = idx & 127;
          int col = c0 + c;
          sh_bs[kk][c] = (col < VV) ? w_out[(size_t)(k0 + kk) * VV + col] : 0.f;
        }
        __syncthreads();
#pragma unroll
        for (int kk = 0; kk < 32; kk++) {
          float bv[4];
#pragma unroll
          for (int cc = 0; cc < 4; cc++) bv[cc] = sh_bs[kk][tx * 4 + cc];
#pragma unroll
          for (int rr = 0; rr < 4; rr++) {
            float av = sh_as[ty * 4 + rr][kk];
#pragma unroll
            for (int cc = 0; cc < 4; cc++) acc[rr][cc] += av * bv[cc];
          }
        }
      }
#pragma unroll
      for (int rr = 0; rr < 4; rr++) {
        int n = n0 + ty * 4 + rr;
#pragma unroll
        for (int cc = 0; cc < 4; cc++) {
          int c = c0 + tx * 4 + cc;
          if (c < VV) logits[(size_t)n * VV + c] = acc[rr][cc];
        }
      }
    }
    gbar();

    if (di == 0) {
      // ============ first-step top-k (32 blocks; replica j=0) =============
      if (bid < BB) {
        const int b = bid;
        const float* row = logits + (size_t)(b * KBM) * VV;
        float tv[5]; int ti[5];
#pragma unroll
        for (int q = 0; q < 5; q++) { tv[q] = -INFINITY; ti[q] = 0x7fffffff; }
        float m = -INFINITY;
        for (int v = tid; v < VV; v += 256) {
          float x = row[v];
          m = fmaxf(m, x);
          top5_insert(tv, ti, x, v);
        }
        sh_red[tid] = m; __syncthreads();
        for (int off = 128; off > 0; off >>= 1) {
          if (tid < off) sh_red[tid] = fmaxf(sh_red[tid], sh_red[tid + off]);
          __syncthreads();
        }
        float rowmax = sh_red[0];
        __syncthreads();
        float s = 0.f;
        for (int v = tid; v < VV; v += 256) s += expf(row[v] - rowmax);
        sh_red[tid] = s; __syncthreads();
        for (int off = 128; off > 0; off >>= 1) {
          if (tid < off) sh_red[tid] += sh_red[tid + off];
          __syncthreads();
        }
        float lse = rowmax + logf(sh_red[0]);
        __syncthreads();
#pragma unroll
        for (int q = 0; q < 5; q++) { sh_sv0[tid * 5 + q] = tv[q]; sh_si0[tid * 5 + q] = ti[q]; }
        __syncthreads();
        int cur = 0;
        for (int off = 128; off > 0; off >>= 1) {
          float* svc = cur ? sh_sv1 : sh_sv0; int* sic = cur ? sh_si1 : sh_si0;
          float* svn = cur ? sh_sv0 : sh_sv1; int* sinn = cur ? sh_si0 : sh_si1;
          if (tid < off) {
            int ia = 0, ib = 0;
            int baseA = tid * 5, baseB = (tid + off) * 5;
#pragma unroll
            for (int q = 0; q < 5; q++) {
              float va = svc[baseA + ia]; int xa = sic[baseA + ia];
              float vb = svc[baseB + ib]; int xb = sic[baseB + ib];
              bool ta = viBetter(va, xa, vb, xb);
              svn[baseA + q] = ta ? va : vb;
              sinn[baseA + q] = ta ? xa : xb;
              ia += ta ? 1 : 0; ib += ta ? 0 : 1;
            }
          }
          cur ^= 1;
          __syncthreads();
        }
        if (tid < KBM) {
          int p = tid;
          int tk = sh_si0[p];
          cum[b * KBM + p] = sh_sv0[p] - lse;
          finished[b * KBM + p] = (tk == EOSID) ? 1 : 0;
          lengths[b * KBM + p] = 1;
          last_tok[b * KBM + p] = tk;
          tokens[b * KBM * MAXLEN + p * MAXLEN + 0] = tk;
        }
        for (int t = tid; t < KBM * HD; t += 256) {
          int p = t >> 9, e2 = t & 511;
          h[(size_t)(b * KBM + p) * HD + e2] = A_cat[(size_t)(b * KBM + p) * 1024 + e2];
        }
      }
      gbar();
    } else {
      // ============ topk phase A (160 blocks: per-row lse + top5) =========
      if (bid < NR) {
        const int row = bid;
        const int j = row % KBM;
        const int fin = finished[row];
        const float cj = cum[row];
        if (fin) {
          if (tid == 0) {
            candV[row * KBM + 0] = cj;            // PAD extension, zero log-prob
            candI[row * KBM + 0] = j * VV + 0;
#pragma unroll
            for (int q = 1; q < KBM; q++) {
              candV[row * KBM + q] = cj + NEGV;
              candI[row * KBM + q] = j * VV + q;
            }
          }
        } else {
          const float* lrow = logits + (size_t)row * VV;
          float tv[5]; int ti[5];
#pragma unroll
          for (int q = 0; q < 5; q++) { tv[q] = -INFINITY; ti[q] = 0x7fffffff; }
          float m = -INFINITY;
          for (int v = tid; v < VV; v += 256) {
            float x = lrow[v];
            m = fmaxf(m, x);
            top5_insert(tv, ti, x, v);
          }
          sh_red[tid] = m; __syncthreads();
          for (int off = 128; off > 0; off >>= 1) {
            if (tid < off) sh_red[tid] = fmaxf(sh_red[tid], sh_red[tid + off]);
            __syncthreads();
          }
          float rowmax = sh_red[0];
          __syncthreads();
          float s = 0.f;
          for (int v = tid; v < VV; v += 256) s += expf(lrow[v] - rowmax);
          sh_red[tid] = s; __syncthreads();
          for (int off = 128; off > 0; off >>= 1) {
            if (tid < off) sh_red[tid] += sh_red[tid + off];
            __syncthreads();
          }
          float lsej = rowmax + logf(sh_red[0]);
          __syncthreads();
#pragma unroll
          for (int q = 0; q < 5; q++) { sh_sv0[tid * 5 + q] = tv[q]; sh_si0[tid * 5 + q] = ti[q]; }
          __syncthreads();
          int cur = 0;
          for (int off = 128; off > 0; off >>= 1) {
            float* svc = cur ? sh_sv1 : sh_sv0; int* sic = cur ? sh_si1 : sh_si0;
            float* svn = cur ? sh_sv0 : sh_sv1; int* sinn = cur ? sh_si0 : sh_si1;
            if (tid < off) {
              int ia = 0, ib = 0;
              int baseA = tid * 5, baseB = (tid + off) * 5;
#pragma unroll
              for (int q = 0; q < 5; q++) {
                float va = svc[baseA + ia]; int xa = sic[baseA + ia];
                float vb = svc[baseB + ib]; int xb = sic[baseB + ib];
                bool ta = viBetter(va, xa, vb, xb);
                svn[baseA + q] = ta ? va : vb;
                sinn[baseA + q] = ta ? xa : xb;
                ia += ta ? 1 : 0; ib += ta ? 0 : 1;
              }
            }
            cur ^= 1;
            __syncthreads();
          }
          if (tid == 0) {
#pragma unroll
            for (int q = 0; q < 5; q++) {
              candV[row * KBM + q] = cj + (sh_sv0[q] - lsej);
              candI[row * KBM + q] = j * VV + sh_si0[q];
            }
          }
        }
      }
      gbar();

      // ============ topk phase B (32 blocks: merge + state update) ========
      if (bid < BB) {
        const int b = bid;
        if (tid < KBM) {
          sh_oc[tid] = cum[b * KBM + tid];
          sh_ofin[tid] = finished[b * KBM + tid];
          sh_olen[tid] = lengths[b * KBM + tid];
        }
        for (int t = tid; t < KBM * MAXLEN; t += 256) sh_ttmp[t] = tokens[b * KBM * MAXLEN + t];
        __syncthreads();
        if (tid == 0) {
          float fv[5]; int fi[5];
#pragma unroll
          for (int q = 0; q < 5; q++) { fv[q] = -INFINITY; fi[q] = 0x7fffffff; }
          for (int t = 0; t < KBM * KBM; t++)
            top5_insert(fv, fi, candV[b * KBM * KBM + t], candI[b * KBM * KBM + t]);
#pragma unroll
          for (int q = 0; q < 5; q++) { sh_selV[q] = fv[q]; sh_selI[q] = fi[q]; }
        }
        __syncthreads();
        if (tid < KBM) {
          int p = tid, idx = sh_selI[p];
          int bm = idx / VV, tk = idx - bm * VV;
          cum[b * KBM + p] = sh_selV[p];
          int pf = sh_ofin[bm];
          lengths[b * KBM + p] = sh_olen[bm] + (pf ? 0 : 1);
          finished[b * KBM + p] = (pf || tk == EOSID) ? 1 : 0;
          last_tok[b * KBM + p] = tk;
        }
        for (int t = tid; t < KBM * MAXLEN; t += 256) {
          int p = t >> 6, pos = t & 63;
          int idx = sh_selI[p]; int bm = idx / VV; int tk = idx - bm * VV;
          tokens[b * KBM * MAXLEN + t] = (pos == di) ? tk : sh_ttmp[bm * MAXLEN + pos];
        }
        for (int t = tid; t < KBM * HD; t += 256) {
          int p = t >> 9, e2 = t & 511;
          int bm = sh_selI[p] / VV;
          h[(size_t)(b * KBM + p) * HD + e2] = A_cat[(size_t)(b * KBM + bm) * 1024 + e2];
        }
      }
      gbar();
    }
  }

  // ================= final: length penalty, best beam, outputs ============
  if (bid < BB) {
    const int b = bid;
    if (tid < KBM) {
      float c = cum[b * KBM + tid];
      float pen = powf((5.0f + (float)lengths[b * KBM + tid]) / 6.0f, 1.2f);
      sh_red[tid] = finished[b * KBM + tid] ? (c / pen) : c;
    }
    __syncthreads();
    if (tid == 0) {
      int best = 0; float bv = sh_red[0];
#pragma unroll
      for (int jj = 1; jj < KBM; jj++) {
        if (sh_red[jj] > bv) { bv = sh_red[jj]; best = jj; }
      }
      sh_selI[0] = best;
    }
    __syncthreads();
    if (tid < MAXLEN)
      out[b * MAXLEN + tid] = (float)tokens[b * KBM * MAXLEN + sh_selI[0] * MAXLEN + tid];
    if (tid < KBM) out[BB * MAXLEN + b * KBM + tid] = cum[b * KBM + tid];
  }
}

extern "C" void kernel_launch(void* const* d_in, const int* in_sizes, int n_in,
                              void* d_out, int out_size, void* d_ws, size_t ws_size,
                              hipStream_t stream) {
  (void)in_sizes; (void)n_in; (void)out_size; (void)ws_size;
  const int*   input_var = (const int*)d_in[0];
  const float* enc       = (const float*)d_in[1];
  const float* emb       = (const float*)d_in[2];
  const float* w_ih      = (const float*)d_in[3];
  const float* w_hh      = (const float*)d_in[4];
  const float* w_out     = (const float*)d_in[5];
  float* out = (float*)d_out;

  float* h      = (float*)d_ws;
  float* A_cat  = h + (size_t)NR * HD;
  float* logits = A_cat + (size_t)NR * 1024;
  int*   tokens = (int*)(logits + (size_t)NR * VV);
  float* cum    = (float*)(tokens + (size_t)BB * KBM * MAXLEN);
  int*   finished = (int*)(cum + NR);
  int*   lengths  = finished + NR;
  int*   last_tok = lengths + NR;
  float* candV  = (float*)(last_tok + NR);
  int*   candI  = (int*)(candV + NR * KBM);
  int*   bar    = (int*)(candI + NR * KBM);

  hipMemsetAsync(bar, 0, 64, stream);
  k_persist<<<NBLK, 256, 0, stream>>>(input_var, enc, emb, w_ih, w_hh, w_out, out,
                                      h, A_cat, logits, tokens, cum, finished,
                                      lengths, last_tok, candV, candI, bar);
}

// Round 3
// 17624.612 us; speedup vs baseline: 4.5421x; 4.5421x over previous
//
#include <hip/hip_runtime.h>
#include <math.h>

// Problem constants
#define BB     32      // batch
#define KBM    5       // beam width
#define NR     160     // BB*KBM rows (beam-major)
#define HD     512     // hidden
#define TT     256     // encoder time steps
#define VV     5000    // vocab
#define MAXLEN 64
#define EOSID  2
#define NEGV   (-1e9f)
#define SCALEF 0.04419417382415922f  // 1/sqrt(512)
#define NBLK   256

// comparator matching jax.lax.top_k stability: value desc, index asc on ties
__device__ __forceinline__ bool viBetter(float av, int ai, float bv, int bi) {
  return (av > bv) || (av == bv && ai < bi);
}

__device__ __forceinline__ void top5_insert(float tv[5], int ti[5], float x, int v) {
  if (!viBetter(x, v, tv[4], ti[4])) return;
  tv[4] = x; ti[4] = v;
#pragma unroll
  for (int q = 4; q > 0; q--) {
    if (viBetter(tv[q], ti[q], tv[q - 1], ti[q - 1])) {
      float tf = tv[q - 1]; int tx2 = ti[q - 1];
      tv[q - 1] = tv[q]; ti[q - 1] = ti[q];
      tv[q] = tf; ti[q] = tx2;
    } else break;
  }
}

__launch_bounds__(256, 1)
__global__ void k_persist(const int* __restrict__ input_var, const float* __restrict__ enc,
                          const float* __restrict__ emb, const float* __restrict__ w_ih,
                          const float* __restrict__ w_hh, const float* __restrict__ w_out,
                          float* __restrict__ out,
                          float* h, float* A_cat, float* logits, int* tokens,
                          float* cum, int* finished, int* lengths, int* last_tok,
                          float* candV, int* candI, int* bar) {
  const int bid = blockIdx.x;
  const int tid = threadIdx.x;
  int bphase = 0;

  // ---- shared memory (~81KB -> 1 block/CU; 256 blocks co-resident) ----
  __shared__ float sh_xs[32][36];         // gru (36: keep 16B-aligned rows)
  __shared__ float sh_hs[32][36];
  __shared__ float sh_ws[6][32][32];
  __shared__ int   sh_toks[32];
  __shared__ float sh_hh[HD];             // attn
  __shared__ float sh_sc[TT];
  __shared__ float sh_red[256];           // reductions
  __shared__ float sh_as[32][33];         // gemm
  __shared__ float sh_bs[32][132];
  __shared__ float sh_sv0[256 * 5]; __shared__ int sh_si0[256 * 5];
  __shared__ float sh_sv1[256 * 5]; __shared__ int sh_si1[256 * 5];
  __shared__ float sh_oc[KBM]; __shared__ int sh_ofin[KBM]; __shared__ int sh_olen[KBM];
  __shared__ int   sh_ttmp[KBM * MAXLEN];
  __shared__ int   sh_selI[KBM]; __shared__ float sh_selV[KBM];

  // ---- grid barrier: release ONCE on arrival, relaxed coherent spin,
  //      acquire fence ONCE on exit. (R2's per-iteration acquire = L2 thrash.)
  auto gbar = [&]() {
    __syncthreads();          // drains vmcnt -> block's writes are in L2
    if (tid == 0) {
      bphase += 1;
      // release RMW: one L2 writeback, then increment at coherence point
      __hip_atomic_fetch_add(bar, 1, __ATOMIC_RELEASE, __HIP_MEMORY_SCOPE_AGENT);
      const int target = bphase * NBLK;
      // relaxed system-scope load: bypasses L1/L2 (coherent), NO cache maintenance
      while (__hip_atomic_load(bar, __ATOMIC_RELAXED, __HIP_MEMORY_SCOPE_SYSTEM) < target) {
        __builtin_amdgcn_s_sleep(4);
      }
      // one acquire fence: invalidate stale L1/L2 before reading peers' data
      __builtin_amdgcn_fence(__ATOMIC_ACQUIRE, "agent");
    }
    __syncthreads();
  };

  // ---- init: h=0, tokens=0, last_tok=SOS ----
  {
    int gidx = bid * 256 + tid;
    const int gstride = NBLK * 256;
    for (int t = gidx; t < NR * HD; t += gstride) h[t] = 0.f;
    for (int t = gidx; t < BB * KBM * MAXLEN; t += gstride) tokens[t] = 0;
    for (int t = gidx; t < NR; t += gstride) last_tok[t] = input_var[t / KBM];
  }
  gbar();

  for (int di = 0; di < MAXLEN; di++) {
    // ================= GRU (80 blocks: 16 col-tiles x 5 row-tiles) =========
    if (bid < 80) {
      const int bx = bid & 15, by = bid >> 4;
      const int tx = tid & 31, ty = tid >> 5;
      const int i0 = bx * 32;
      const int n0 = by * 32;
      if (tid < 32) sh_toks[tid] = last_tok[n0 + tid];
      float acc[6][4];
#pragma unroll
      for (int g = 0; g < 6; g++)
#pragma unroll
        for (int rr = 0; rr < 4; rr++) acc[g][rr] = 0.f;

      for (int k0 = 0; k0 < HD; k0 += 32) {
        __syncthreads();
        {
          // x/h tiles: one float4 per thread each (32 rows x 8 vec4)
          int r = tid >> 3, c4 = (tid & 7) * 4;
          *reinterpret_cast<float4*>(&sh_xs[r][c4]) =
              *reinterpret_cast<const float4*>(&emb[(size_t)sh_toks[r] * HD + k0 + c4]);
          *reinterpret_cast<float4*>(&sh_hs[r][c4]) =
              *reinterpret_cast<const float4*>(&h[(size_t)(n0 + r) * HD + k0 + c4]);
        }
#pragma unroll
        for (int g = 0; g < 6; g++) {
          // weights: 6 gates x (32 kk x 8 vec4) = one float4 per thread per gate
          int kk = tid >> 3, c4 = (tid & 7) * 4;
          const float* W = (g < 3) ? w_ih : w_hh;
          int gc = (g < 3) ? g : (g - 3);
          *reinterpret_cast<float4*>(&sh_ws[g][kk][c4]) =
              *reinterpret_cast<const float4*>(&W[(size_t)(k0 + kk) * 1536 + gc * HD + i0 + c4]);
        }
        __syncthreads();
#pragma unroll
        for (int kk = 0; kk < 32; kk++) {
          float w0 = sh_ws[0][kk][tx], w1 = sh_ws[1][kk][tx], w2 = sh_ws[2][kk][tx];
          float w3 = sh_ws[3][kk][tx], w4 = sh_ws[4][kk][tx], w5 = sh_ws[5][kk][tx];
#pragma unroll
          for (int rr = 0; rr < 4; rr++) {
            float xv = sh_xs[ty * 4 + rr][kk];
            float hv = sh_hs[ty * 4 + rr][kk];
            acc[0][rr] += xv * w0;
            acc[1][rr] += xv * w1;
            acc[2][rr] += xv * w2;
            acc[3][rr] += hv * w3;
            acc[4][rr] += hv * w4;
            acc[5][rr] += hv * w5;
          }
        }
      }
#pragma unroll
      for (int rr = 0; rr < 4; rr++) {
        int n = n0 + ty * 4 + rr;
        int i = i0 + tx;
        float hv = h[(size_t)n * HD + i];
        float z = 1.f / (1.f + expf(-(acc[0][rr] + acc[3][rr])));
        float r = 1.f / (1.f + expf(-(acc[1][rr] + acc[4][rr])));
        float nn = tanhf(acc[2][rr] + r * acc[5][rr]);
        A_cat[(size_t)n * 1024 + i] = (1.f - z) * nn + z * hv;
      }
    }
    gbar();

    // ================= attention (160 blocks: one per row) =================
    if (bid < NR) {
      const int n = bid;
      const int b = n / KBM;
      sh_hh[tid] = A_cat[(size_t)n * 1024 + tid];
      sh_hh[tid + 256] = A_cat[(size_t)n * 1024 + tid + 256];
      __syncthreads();
      const float* ep = enc + ((size_t)b * TT + tid) * HD;
      float acc = 0.f;
      for (int k = 0; k < HD; k += 4) {
        float4 e = *reinterpret_cast<const float4*>(ep + k);
        acc += sh_hh[k] * e.x + sh_hh[k + 1] * e.y + sh_hh[k + 2] * e.z + sh_hh[k + 3] * e.w;
      }
      float s = acc * SCALEF;
      sh_red[tid] = s;
      __syncthreads();
      for (int off = 128; off > 0; off >>= 1) {
        if (tid < off) sh_red[tid] = fmaxf(sh_red[tid], sh_red[tid + off]);
        __syncthreads();
      }
      float m = sh_red[0];
      __syncthreads();
      float e = expf(s - m);
      sh_red[tid] = e;
      __syncthreads();
      for (int off = 128; off > 0; off >>= 1) {
        if (tid < off) sh_red[tid] += sh_red[tid + off];
        __syncthreads();
      }
      float S = sh_red[0];
      __syncthreads();
      sh_sc[tid] = e / S;
      __syncthreads();
      // context: thread handles columns (2*tid, 2*tid+1) via float2
      {
        float cx = 0.f, cy = 0.f;
        const float* eb = enc + (size_t)b * TT * HD + 2 * tid;
        for (int t = 0; t < TT; t++) {
          float2 e2 = *reinterpret_cast<const float2*>(eb + (size_t)t * HD);
          float w = sh_sc[t];
          cx += w * e2.x; cy += w * e2.y;
        }
        float2 o2; o2.x = cx; o2.y = cy;
        *reinterpret_cast<float2*>(&A_cat[(size_t)n * 1024 + HD + 2 * tid]) = o2;
      }
    }
    gbar();

    // ================= output GEMM (200 blocks: 40 col x 5 row tiles) ======
    if (bid < 200) {
      const int tx = tid & 31, ty = tid >> 5;
      const int c0 = (bid % 40) * 128;
      const int n0 = (bid / 40) * 32;
      float acc[4][4];
#pragma unroll
      for (int rr = 0; rr < 4; rr++)
#pragma unroll
        for (int cc = 0; cc < 4; cc++) acc[rr][cc] = 0.f;

      for (int k0 = 0; k0 < 1024; k0 += 32) {
        __syncthreads();
#pragma unroll
        for (int p = 0; p < 4; p++) {
          int idx = tid + p * 256;
          int r = idx >> 5, kk = idx & 31;
          sh_as[r][kk] = A_cat[(size_t)(n0 + r) * 1024 + k0 + kk];
        }
#pragma unroll
        for (int p = 0; p < 4; p++) {
          int idx = tid + p * 256;      // 0..1023: 32 kk x 32 vec4
          int kk = idx >> 5;
          int c4 = (idx & 31) * 4;
          int col = c0 + c4;
          float4 v;
          if (col + 3 < VV) {
            v = *reinterpret_cast<const float4*>(&w_out[(size_t)(k0 + kk) * VV + col]);
          } else {
            v.x = v.y = v.z = v.w = 0.f;   // col%4==0 -> fully OOB here
          }
          *reinterpret_cast<float4*>(&sh_bs[kk][c4]) = v;
        }
        __syncthreads();
#pragma unroll
        for (int kk = 0; kk < 32; kk++) {
          float bv[4];
#pragma unroll
          for (int cc = 0; cc < 4; cc++) bv[cc] = sh_bs[kk][tx * 4 + cc];
#pragma unroll
          for (int rr = 0; rr < 4; rr++) {
            float av = sh_as[ty * 4 + rr][kk];
#pragma unroll
            for (int cc = 0; cc < 4; cc++) acc[rr][cc] += av * bv[cc];
          }
        }
      }
#pragma unroll
      for (int rr = 0; rr < 4; rr++) {
        int n = n0 + ty * 4 + rr;
#pragma unroll
        for (int cc = 0; cc < 4; cc++) {
          int c = c0 + tx * 4 + cc;
          if (c < VV) logits[(size_t)n * VV + c] = acc[rr][cc];
        }
      }
    }
    gbar();

    if (di == 0) {
      // ============ first-step top-k (32 blocks; replica j=0) =============
      if (bid < BB) {
        const int b = bid;
        const float* row = logits + (size_t)(b * KBM) * VV;
        float tv[5]; int ti[5];
#pragma unroll
        for (int q = 0; q < 5; q++) { tv[q] = -INFINITY; ti[q] = 0x7fffffff; }
        float m = -INFINITY;
        for (int v = tid; v < VV; v += 256) {
          float x = row[v];
          m = fmaxf(m, x);
          top5_insert(tv, ti, x, v);
        }
        sh_red[tid] = m; __syncthreads();
        for (int off = 128; off > 0; off >>= 1) {
          if (tid < off) sh_red[tid] = fmaxf(sh_red[tid], sh_red[tid + off]);
          __syncthreads();
        }
        float rowmax = sh_red[0];
        __syncthreads();
        float s = 0.f;
        for (int v = tid; v < VV; v += 256) s += expf(row[v] - rowmax);
        sh_red[tid] = s; __syncthreads();
        for (int off = 128; off > 0; off >>= 1) {
          if (tid < off) sh_red[tid] += sh_red[tid + off];
          __syncthreads();
        }
        float lse = rowmax + logf(sh_red[0]);
        __syncthreads();
#pragma unroll
        for (int q = 0; q < 5; q++) { sh_sv0[tid * 5 + q] = tv[q]; sh_si0[tid * 5 + q] = ti[q]; }
        __syncthreads();
        int cur = 0;
        for (int off = 128; off > 0; off >>= 1) {
          float* svc = cur ? sh_sv1 : sh_sv0; int* sic = cur ? sh_si1 : sh_si0;
          float* svn = cur ? sh_sv0 : sh_sv1; int* sinn = cur ? sh_si0 : sh_si1;
          if (tid < off) {
            int ia = 0, ib = 0;
            int baseA = tid * 5, baseB = (tid + off) * 5;
#pragma unroll
            for (int q = 0; q < 5; q++) {
              float va = svc[baseA + ia]; int xa = sic[baseA + ia];
              float vb = svc[baseB + ib]; int xb = sic[baseB + ib];
              bool ta = viBetter(va, xa, vb, xb);
              svn[baseA + q] = ta ? va : vb;
              sinn[baseA + q] = ta ? xa : xb;
              ia += ta ? 1 : 0; ib += ta ? 0 : 1;
            }
          }
          cur ^= 1;
          __syncthreads();
        }
        if (tid < KBM) {
          int p = tid;
          int tk = sh_si0[p];
          cum[b * KBM + p] = sh_sv0[p] - lse;
          finished[b * KBM + p] = (tk == EOSID) ? 1 : 0;
          lengths[b * KBM + p] = 1;
          last_tok[b * KBM + p] = tk;
          tokens[b * KBM * MAXLEN + p * MAXLEN + 0] = tk;
        }
        for (int t = tid; t < KBM * HD; t += 256) {
          int p = t >> 9, e2 = t & 511;
          h[(size_t)(b * KBM + p) * HD + e2] = A_cat[(size_t)(b * KBM + p) * 1024 + e2];
        }
      }
      gbar();
    } else {
      // ============ topk phase A (160 blocks: per-row lse + top5) =========
      if (bid < NR) {
        const int row = bid;
        const int j = row % KBM;
        const int fin = finished[row];
        const float cj = cum[row];
        if (fin) {
          if (tid == 0) {
            candV[row * KBM + 0] = cj;            // PAD extension, zero log-prob
            candI[row * KBM + 0] = j * VV + 0;
#pragma unroll
            for (int q = 1; q < KBM; q++) {
              candV[row * KBM + q] = cj + NEGV;
              candI[row * KBM + q] = j * VV + q;
            }
          }
        } else {
          const float* lrow = logits + (size_t)row * VV;
          float tv[5]; int ti[5];
#pragma unroll
          for (int q = 0; q < 5; q++) { tv[q] = -INFINITY; ti[q] = 0x7fffffff; }
          float m = -INFINITY;
          for (int v = tid; v < VV; v += 256) {
            float x = lrow[v];
            m = fmaxf(m, x);
            top5_insert(tv, ti, x, v);
          }
          sh_red[tid] = m; __syncthreads();
          for (int off = 128; off > 0; off >>= 1) {
            if (tid < off) sh_red[tid] = fmaxf(sh_red[tid], sh_red[tid + off]);
            __syncthreads();
          }
          float rowmax = sh_red[0];
          __syncthreads();
          float s = 0.f;
          for (int v = tid; v < VV; v += 256) s += expf(lrow[v] - rowmax);
          sh_red[tid] = s; __syncthreads();
          for (int off = 128; off > 0; off >>= 1) {
            if (tid < off) sh_red[tid] += sh_red[tid + off];
            __syncthreads();
          }
          float lsej = rowmax + logf(sh_red[0]);
          __syncthreads();
#pragma unroll
          for (int q = 0; q < 5; q++) { sh_sv0[tid * 5 + q] = tv[q]; sh_si0[tid * 5 + q] = ti[q]; }
          __syncthreads();
          int cur = 0;
          for (int off = 128; off > 0; off >>= 1) {
            float* svc = cur ? sh_sv1 : sh_sv0; int* sic = cur ? sh_si1 : sh_si0;
            float* svn = cur ? sh_sv0 : sh_sv1; int* sinn = cur ? sh_si0 : sh_si1;
            if (tid < off) {
              int ia = 0, ib = 0;
              int baseA = tid * 5, baseB = (tid + off) * 5;
#pragma unroll
              for (int q = 0; q < 5; q++) {
                float va = svc[baseA + ia]; int xa = sic[baseA + ia];
                float vb = svc[baseB + ib]; int xb = sic[baseB + ib];
                bool ta = viBetter(va, xa, vb, xb);
                svn[baseA + q] = ta ? va : vb;
                sinn[baseA + q] = ta ? xa : xb;
                ia += ta ? 1 : 0; ib += ta ? 0 : 1;
              }
            }
            cur ^= 1;
            __syncthreads();
          }
          if (tid == 0) {
#pragma unroll
            for (int q = 0; q < 5; q++) {
              candV[row * KBM + q] = cj + (sh_sv0[q] - lsej);
              candI[row * KBM + q] = j * VV + sh_si0[q];
            }
          }
        }
      }
      gbar();

      // ============ topk phase B (32 blocks: merge + state update) ========
      if (bid < BB) {
        const int b = bid;
        if (tid < KBM) {
          sh_oc[tid] = cum[b * KBM + tid];
          sh_ofin[tid] = finished[b * KBM + tid];
          sh_olen[tid] = lengths[b * KBM + tid];
        }
        for (int t = tid; t < KBM * MAXLEN; t += 256) sh_ttmp[t] = tokens[b * KBM * MAXLEN + t];
        __syncthreads();
        if (tid == 0) {
          float fv[5]; int fi[5];
#pragma unroll
          for (int q = 0; q < 5; q++) { fv[q] = -INFINITY; fi[q] = 0x7fffffff; }
          for (int t = 0; t < KBM * KBM; t++)
            top5_insert(fv, fi, candV[b * KBM * KBM + t], candI[b * KBM * KBM + t]);
#pragma unroll
          for (int q = 0; q < 5; q++) { sh_selV[q] = fv[q]; sh_selI[q] = fi[q]; }
        }
        __syncthreads();
        if (tid < KBM) {
          int p = tid, idx = sh_selI[p];
          int bm = idx / VV, tk = idx - bm * VV;
          cum[b * KBM + p] = sh_selV[p];
          int pf = sh_ofin[bm];
          lengths[b * KBM + p] = sh_olen[bm] + (pf ? 0 : 1);
          finished[b * KBM + p] = (pf || tk == EOSID) ? 1 : 0;
          last_tok[b * KBM + p] = tk;
        }
        for (int t = tid; t < KBM * MAXLEN; t += 256) {
          int p = t >> 6, pos = t & 63;
          int idx = sh_selI[p]; int bm = idx / VV; int tk = idx - bm * VV;
          tokens[b * KBM * MAXLEN + t] = (pos == di) ? tk : sh_ttmp[bm * MAXLEN + pos];
        }
        for (int t = tid; t < KBM * HD; t += 256) {
          int p = t >> 9, e2 = t & 511;
          int bm = sh_selI[p] / VV;
          h[(size_t)(b * KBM + p) * HD + e2] = A_cat[(size_t)(b * KBM + bm) * 1024 + e2];
        }
      }
      gbar();
    }
  }

  // ================= final: length penalty, best beam, outputs ============
  if (bid < BB) {
    const int b = bid;
    if (tid < KBM) {
      float c = cum[b * KBM + tid];
      float pen = powf((5.0f + (float)lengths[b * KBM + tid]) / 6.0f, 1.2f);
      sh_red[tid] = finished[b * KBM + tid] ? (c / pen) : c;
    }
    __syncthreads();
    if (tid == 0) {
      int best = 0; float bv = sh_red[0];
#pragma unroll
      for (int jj = 1; jj < KBM; jj++) {
        if (sh_red[jj] > bv) { bv = sh_red[jj]; best = jj; }
      }
      sh_selI[0] = best;
    }
    __syncthreads();
    if (tid < MAXLEN)
      out[b * MAXLEN + tid] = (float)tokens[b * KBM * MAXLEN + sh_selI[0] * MAXLEN + tid];
    if (tid < KBM) out[BB * MAXLEN + b * KBM + tid] = cum[b * KBM + tid];
  }
}

extern "C" void kernel_launch(void* const* d_in, const int* in_sizes, int n_in,
                              void* d_out, int out_size, void* d_ws, size_t ws_size,
                              hipStream_t stream) {
  (void)in_sizes; (void)n_in; (void)out_size; (void)ws_size;
  const int*   input_var = (const int*)d_in[0];
  const float* enc       = (const float*)d_in[1];
  const float* emb       = (const float*)d_in[2];
  const float* w_ih      = (const float*)d_in[3];
  const float* w_hh      = (const float*)d_in[4];
  const float* w_out     = (const float*)d_in[5];
  float* out = (float*)d_out;

  float* h      = (float*)d_ws;
  float* A_cat  = h + (size_t)NR * HD;
  float* logits = A_cat + (size_t)NR * 1024;
  int*   tokens = (int*)(logits + (size_t)NR * VV);
  float* cum    = (float*)(tokens + (size_t)BB * KBM * MAXLEN);
  int*   finished = (int*)(cum + NR);
  int*   lengths  = finished + NR;
  int*   last_tok = lengths + NR;
  float* candV  = (float*)(last_tok + NR);
  int*   candI  = (int*)(candV + NR * KBM);
  int*   bar    = (int*)(candI + NR * KBM);

  hipMemsetAsync(bar, 0, 64, stream);
  k_persist<<<NBLK, 256, 0, stream>>>(input_var, enc, emb, w_ih, w_hh, w_out, out,
                                      h, A_cat, logits, tokens, cum, finished,
                                      lengths, last_tok, candV, candI, bar);
}